// Round 4
// baseline (405.525 us; speedup 1.0000x reference)
//
#include <hip/hip_runtime.h>
#include <stdint.h>

// ---------------------------------------------------------------------------
// Fused LSTM cell, round 4: NO LDS, NO BARRIERS.
//  prep_w: W -> fragment-contiguous bf16 blobs Bt[bn][fid][chunk][lane][8]
//          (d_ws, 786 KiB, L2-resident; fid = g*2+wc). Unchanged from r3.
//  lstm_main: register-tiled GEMM. Each lane loads its A-fragment directly
//          from global fp32 (16 rows x 128B/wave, coalesced; 8 bn-sibling
//          blocks L2-hit via XCD swizzle), converts via v_cvt_pk_bf16_f32,
//          MFMA 16x16x32. 12 unrolled K-chunks, zero sync points ->
//          compiler software-pipelines, 12 independent waves/CU hide HBM.
// ---------------------------------------------------------------------------

typedef short          bf16x8 __attribute__((ext_vector_type(8)));
typedef unsigned short u16x8  __attribute__((ext_vector_type(8)));
typedef float          f32x4  __attribute__((ext_vector_type(4)));
typedef unsigned int   u32x4  __attribute__((ext_vector_type(4)));

#define HDIM   256
#define INDIM  100
#define NROWS  131072

__device__ __forceinline__ float fexp(float x) {
  return __builtin_amdgcn_exp2f(x * 1.44269504088896340736f);
}
__device__ __forceinline__ float frcp(float x) { return __builtin_amdgcn_rcpf(x); }
__device__ __forceinline__ float sigm(float x) { return frcp(1.0f + fexp(-x)); }
__device__ __forceinline__ float tanh_fast(float x) {
  return 1.0f - 2.0f * frcp(1.0f + fexp(2.0f * x));
}
__device__ __forceinline__ unsigned short f2bf_rne(float f) {
  union { float f; uint32_t u; } v; v.f = f;
  return (unsigned short)((v.u + 0x7FFFu + ((v.u >> 16) & 1u)) >> 16);
}
__device__ __forceinline__ unsigned int cvt_pk_bf16(float lo, float hi) {
  unsigned int r;
  asm("v_cvt_pk_bf16_f32 %0, %1, %2" : "=v"(r) : "v"(lo), "v"(hi));
  return r;
}

// ---- prep: one unit = (bn*8+fid)*12 + chunk; 64 lanes x 8 k-elems ---------
__global__ void prep_w(const float* __restrict__ Wx, const float* __restrict__ Wh,
                       unsigned short* __restrict__ Bt) {
  const int unit = blockIdx.x * 4 + (threadIdx.x >> 6);   // 0..767
  const int lane = threadIdx.x & 63;
  const int kst  = unit % 12;
  const int fidb = unit / 12;            // bn*8 + fid
  const int bn   = fidb >> 3, fid = fidb & 7;
  const int g    = fid >> 1,  wc  = fid & 1;
  const int wcol = g * HDIM + bn * 32 + wc * 16 + (lane & 15);
  const int kb   = kst * 32 + (lane >> 4) * 8;
  unsigned short v[8];
#pragma unroll
  for (int e = 0; e < 8; ++e) {
    const int k = kb + e;                // 0..383; [100,128) zero pad
    float f = 0.0f;
    if (k < INDIM)       f = Wx[(size_t)k * 1024 + wcol];
    else if (k >= 128)   f = Wh[(size_t)(k - 128) * 1024 + wcol];
    v[e] = f2bf_rne(f);
  }
  *reinterpret_cast<u16x8*>(Bt + (size_t)unit * 512 + lane * 8) =
      *reinterpret_cast<u16x8*>(v);
}

// ---- main -----------------------------------------------------------------
__global__ __launch_bounds__(256, 3)
void lstm_main(const float* __restrict__ X, const float* __restrict__ Cin,
               const float* __restrict__ Hin,
               const unsigned short* __restrict__ Bt,
               const float* __restrict__ bxp, const float* __restrict__ bhp,
               float* __restrict__ out)
{
  const int tid  = threadIdx.x;
  const int orig = blockIdx.x;                 // 0..8191 (%8==0 -> bijective)
  const int lg   = ((orig & 7) << 10) | (orig >> 3);
  const int mt   = lg >> 3;                    // M tile 0..1023 (128 rows)
  const int bn   = lg & 7;                     // N tile 0..7 (32 H-cols)

  const int lane = tid & 63;
  const int l15  = lane & 15;
  const int kq   = lane >> 4;                  // k-quarter 0..3
  const int wid  = tid >> 6;                   // 0..3
  const int wr   = wid >> 1;                   // 0..1: 64-row group
  const int wc   = wid & 1;                    // 0..1: 16-hcol half
  const int ch   = bn * 32 + wc * 16 + l15;    // this lane's H column

  // per-m A row pointers (fragment rows), pre-offset by kq*8
  const float* xrp[4];
  const float* hrp[4];
#pragma unroll
  for (int m = 0; m < 4; ++m) {
    const int row = mt * 128 + wr * 64 + m * 16 + l15;
    xrp[m] = X   + (size_t)row * INDIM + kq * 8;
    hrp[m] = Hin + (size_t)row * HDIM + kq * 8;
  }
  const unsigned short* btp[4];
#pragma unroll
  for (int g = 0; g < 4; ++g)
    btp[g] = Bt + (size_t)((bn * 8 + g * 2 + wc) * 12) * 512 + lane * 8;

  f32x4 acc[4][4];                             // [m][gate]
#pragma unroll
  for (int m = 0; m < 4; ++m)
#pragma unroll
    for (int g = 0; g < 4; ++g)
#pragma unroll
      for (int e = 0; e < 4; ++e) acc[m][g][e] = 0.0f;

  // 12 unrolled K-chunks (0-3: x, k zero-padded 100->128; 4-11: h)
#pragma unroll
  for (int c = 0; c < 12; ++c) {
    bf16x8 bfr[4];
#pragma unroll
    for (int g = 0; g < 4; ++g)
      bfr[g] = *reinterpret_cast<const bf16x8*>(btp[g] + c * 512);

    bf16x8 afr[4];
#pragma unroll
    for (int m = 0; m < 4; ++m) {
      float4 lo = make_float4(0.f, 0.f, 0.f, 0.f);
      float4 hi = make_float4(0.f, 0.f, 0.f, 0.f);
      if (c < 3) {            // x, fully in-bounds (k <= 96 <= 100)
        lo = *reinterpret_cast<const float4*>(xrp[m] + c * 32);
        hi = *reinterpret_cast<const float4*>(xrp[m] + c * 32 + 4);
      } else if (c == 3) {    // x tail: only kq==0 lo (k=96..99) valid
        if (kq == 0) lo = *reinterpret_cast<const float4*>(xrp[m] + 96);
      } else {                // h, fully in-bounds
        lo = *reinterpret_cast<const float4*>(hrp[m] + (c - 4) * 32);
        hi = *reinterpret_cast<const float4*>(hrp[m] + (c - 4) * 32 + 4);
      }
      union { u32x4 u; bf16x8 b; } cv;
      cv.u[0] = cvt_pk_bf16(lo.x, lo.y);
      cv.u[1] = cvt_pk_bf16(lo.z, lo.w);
      cv.u[2] = cvt_pk_bf16(hi.x, hi.y);
      cv.u[3] = cvt_pk_bf16(hi.z, hi.w);
      afr[m] = cv.b;
    }

    __builtin_amdgcn_s_setprio(1);
#pragma unroll
    for (int m = 0; m < 4; ++m)
#pragma unroll
      for (int g = 0; g < 4; ++g)
        acc[m][g] = __builtin_amdgcn_mfma_f32_16x16x32_bf16(
            afr[m], bfr[g], acc[m][g], 0, 0, 0);
    __builtin_amdgcn_s_setprio(0);
  }

  // ---- epilogue: lane-local gate combine (D: col=lane&15, row=kq*4+e) ----
  float bias[4];
#pragma unroll
  for (int g = 0; g < 4; ++g) bias[g] = bxp[g * HDIM + ch] + bhp[g * HDIM + ch];

  float cvv[4][4];
  const float* cbase = Cin + (size_t)(mt * 128 + wr * 64 + kq * 4) * HDIM + ch;
#pragma unroll
  for (int m = 0; m < 4; ++m)
#pragma unroll
    for (int e = 0; e < 4; ++e)
      cvv[m][e] = cbase[(size_t)(m * 16 + e) * HDIM];

  float* obase = out + (size_t)(mt * 128 + wr * 64 + kq * 4) * HDIM + ch;
  float* obase2 = obase + (size_t)NROWS * HDIM;
#pragma unroll
  for (int m = 0; m < 4; ++m) {
#pragma unroll
    for (int e = 0; e < 4; ++e) {
      const float pi = acc[m][0][e] + bias[0];
      const float pf = acc[m][1][e] + bias[1];
      const float pg = acc[m][2][e] + bias[2];
      const float po = acc[m][3][e] + bias[3];
      const float ig = sigm(pi), fg = sigm(pf);
      const float gg = tanh_fast(pg), og = sigm(po);
      const float co = fg * cvv[m][e] + ig * gg;
      const float ho = og * tanh_fast(co);
      obase [(size_t)(m * 16 + e) * HDIM] = co;
      obase2[(size_t)(m * 16 + e) * HDIM] = ho;
    }
  }
}

extern "C" void kernel_launch(void* const* d_in, const int* in_sizes, int n_in,
                              void* d_out, int out_size, void* d_ws, size_t ws_size,
                              hipStream_t stream) {
  const float* x  = (const float*)d_in[0];
  const float* C  = (const float*)d_in[1];
  const float* h  = (const float*)d_in[2];
  const float* Wx = (const float*)d_in[3];
  const float* Wh = (const float*)d_in[4];
  const float* bx = (const float*)d_in[5];
  const float* bh = (const float*)d_in[6];
  float* o = (float*)d_out;
  unsigned short* Bt = (unsigned short*)d_ws;   // 768*512*2 = 786 KiB

  prep_w<<<dim3(192), dim3(256), 0, stream>>>(Wx, Wh, Bt);
  lstm_main<<<dim3(8192), dim3(256), 0, stream>>>(x, C, h, Bt, bx, bh, o);
}

// Round 5
// 236.374 us; speedup vs baseline: 1.7156x; 1.7156x over previous
//
#include <hip/hip_runtime.h>
#include <stdint.h>

// ---------------------------------------------------------------------------
// Fused LSTM cell, round 5 = round 3 + real software pipeline (T3/T4).
//  - raw s_barrier with lgkmcnt(0) only (no vmcnt drain -> global loads stay
//    in flight across barriers)
//  - A prefetch distance 2 via two named register sets avA/avB
//  - B fragments issued at stage top; C/bias prefetched at stage 4
//  - everything else identical to r3 (tile 128x128, per-wave 64x64,
//    XOR-swizzled A-LDS dbuf, fragment-packed Bt in d_ws, lane-local epilogue)
// ---------------------------------------------------------------------------

typedef short          bf16x8 __attribute__((ext_vector_type(8)));
typedef unsigned short u16x8  __attribute__((ext_vector_type(8)));
typedef float          f32x4  __attribute__((ext_vector_type(4)));

#define HDIM   256
#define INDIM  100
#define NROWS  131072
#define NSTAGE 6              // 6 x BK=64 : 2 x-stages (pad 128) + 4 h-stages

// barrier WITHOUT vmcnt drain: LDS-drain + barrier only
#define BAR() asm volatile("s_waitcnt lgkmcnt(0)\n\ts_barrier" ::: "memory")

__device__ __forceinline__ float fexp(float x) {
  return __builtin_amdgcn_exp2f(x * 1.44269504088896340736f);
}
__device__ __forceinline__ float frcp(float x) { return __builtin_amdgcn_rcpf(x); }
__device__ __forceinline__ float sigm(float x) { return frcp(1.0f + fexp(-x)); }
__device__ __forceinline__ float tanh_fast(float x) {
  return 1.0f - 2.0f * frcp(1.0f + fexp(2.0f * x));
}
__device__ __forceinline__ unsigned short f2bf_rne(float f) {
  union { float f; uint32_t u; } v; v.f = f;
  return (unsigned short)((v.u + 0x7FFFu + ((v.u >> 16) & 1u)) >> 16);
}
__device__ __forceinline__ unsigned int cvt_pk_bf16(float lo, float hi) {
  unsigned int r;
  asm("v_cvt_pk_bf16_f32 %0, %1, %2" : "=v"(r) : "v"(lo), "v"(hi));
  return r;
}

// ---- prep: one unit = (bn*8+fid)*12 + chunk; 64 lanes x 8 k-elems ---------
__global__ void prep_w(const float* __restrict__ Wx, const float* __restrict__ Wh,
                       unsigned short* __restrict__ Bt) {
  const int unit = blockIdx.x * 4 + (threadIdx.x >> 6);   // 0..767
  const int lane = threadIdx.x & 63;
  const int kst  = unit % 12;
  const int fidb = unit / 12;            // bn*8 + fid
  const int bn   = fidb >> 3, fid = fidb & 7;
  const int g    = fid >> 1,  wc  = fid & 1;
  const int wcol = g * HDIM + bn * 32 + wc * 16 + (lane & 15);
  const int kb   = kst * 32 + (lane >> 4) * 8;
  unsigned short v[8];
#pragma unroll
  for (int e = 0; e < 8; ++e) {
    const int k = kb + e;                // 0..383; [100,128) zero pad
    float f = 0.0f;
    if (k < INDIM)       f = Wx[(size_t)k * 1024 + wcol];
    else if (k >= 128)   f = Wh[(size_t)(k - 128) * 1024 + wcol];
    v[e] = f2bf_rne(f);
  }
  *reinterpret_cast<u16x8*>(Bt + (size_t)unit * 512 + lane * 8) =
      *reinterpret_cast<u16x8*>(v);
}

// ---- main -----------------------------------------------------------------
__global__ __launch_bounds__(256, 2)
void lstm_main(const float* __restrict__ X, const float* __restrict__ Cin,
               const float* __restrict__ Hin,
               const unsigned short* __restrict__ Bt,
               const float* __restrict__ bxp, const float* __restrict__ bhp,
               float* __restrict__ out)
{
  __shared__ unsigned short As[2][128 * 64];   // 32 KiB total

  const int tid  = threadIdx.x;
  const int orig = blockIdx.x;                 // 0..8191 (%8==0 -> bijective)
  const int lg   = ((orig & 7) << 10) | (orig >> 3);
  const int mt   = lg >> 3;                    // M tile 0..1023 (128 rows)
  const int bn   = lg & 7;                     // N tile 0..7 (32 H-cols)

  const int lane = tid & 63;
  const int l15  = lane & 15;
  const int kq   = lane >> 4;
  const int wid  = tid >> 6;                   // 0..3
  const int wr   = wid >> 1;                   // 0..1: 64-row group
  const int wc   = wid & 1;                    // 0..1: 16-hcol half
  const int ch   = bn * 32 + wc * 16 + l15;    // this lane's H column

  f32x4 acc[4][4];                             // [m][gate]
#pragma unroll
  for (int m = 0; m < 4; ++m)
#pragma unroll
    for (int g = 0; g < 4; ++g)
#pragma unroll
      for (int e = 0; e < 4; ++e) acc[m][g][e] = 0.0f;

  float avA[32], avB[32];                      // 2-deep A prefetch regs

  auto stage_load = [&](int s, float (&av)[32]) {
    const bool   xph = (s < 2);
    const float* Ap  = xph ? X : Hin;
    const int    lda = xph ? INDIM : HDIM;
    const int    kb  = xph ? s * 64 : (s - 2) * 64;
#pragma unroll
    for (int i = 0; i < 4; ++i) {
      const int ci = i * 256 + tid;            // flat 16B-chunk index 0..1023
      const int r  = ci >> 3, c = ci & 7;
      const int k0 = kb + c * 8;
      const float* p = Ap + (size_t)(mt * 128 + r) * lda + k0;
      float4 lo = make_float4(0.f, 0.f, 0.f, 0.f);
      float4 hi = make_float4(0.f, 0.f, 0.f, 0.f);
      if (k0 + 4 <= lda) lo = *reinterpret_cast<const float4*>(p);
      if (k0 + 8 <= lda) hi = *reinterpret_cast<const float4*>(p + 4);
      av[i*8+0]=lo.x; av[i*8+1]=lo.y; av[i*8+2]=lo.z; av[i*8+3]=lo.w;
      av[i*8+4]=hi.x; av[i*8+5]=hi.y; av[i*8+6]=hi.z; av[i*8+7]=hi.w;
    }
  };

  auto stage_write = [&](int b, float (&av)[32]) {
#pragma unroll
    for (int i = 0; i < 4; ++i) {
      const int ci = i * 256 + tid;
      const int r  = ci >> 3, c = ci & 7;
      unsigned int u[4];
#pragma unroll
      for (int j = 0; j < 4; ++j)
        u[j] = cvt_pk_bf16(av[i*8 + 2*j], av[i*8 + 2*j + 1]);
      *reinterpret_cast<uint4*>(&As[b][r * 64 + ((c ^ (r & 7)) * 8)]) =
          *reinterpret_cast<uint4*>(u);
    }
  };

  // prologue: 2 stages of A in flight, stage 0 staged to LDS
  stage_load(0, avA);
  stage_load(1, avB);
  stage_write(0, avA);                         // auto-vmcnt waits avA only
  BAR();

  float cvv[16];
  float bias[4];
  const float* cbase = Cin + (size_t)(mt * 128 + wr * 64 + kq * 4) * HDIM + ch;

#pragma unroll
  for (int s = 0; s < NSTAGE; ++s) {
    // B fragments for this stage: 8 coalesced 16B/lane loads from L2. First.
    bf16x8 bfr[2][4];
#pragma unroll
    for (int kk = 0; kk < 2; ++kk)
#pragma unroll
      for (int g = 0; g < 4; ++g) {
        const size_t off =
            ((size_t)((bn * 8 + g * 2 + wc) * 12 + (s * 2 + kk))) * 512 + lane * 8;
        bfr[kk][g] = *reinterpret_cast<const bf16x8*>(Bt + off);
      }

    // A prefetch, distance 2 (consumed by stage_write at stage s+1 end)
    if (s + 2 < NSTAGE) {
      if ((s & 1) == 0) stage_load(s + 2, avA);
      else              stage_load(s + 2, avB);
    }
    // epilogue prefetch: C tile + bias, two stages early
    if (s == 4) {
#pragma unroll
      for (int m = 0; m < 4; ++m)
#pragma unroll
        for (int e = 0; e < 4; ++e)
          cvv[m * 4 + e] = cbase[(size_t)(m * 16 + e) * HDIM];
#pragma unroll
      for (int g = 0; g < 4; ++g)
        bias[g] = bxp[g * HDIM + ch] + bhp[g * HDIM + ch];
    }

    const unsigned short* Ab = As[s & 1];
#pragma unroll
    for (int kk = 0; kk < 2; ++kk) {
      bf16x8 afr[4];
#pragma unroll
      for (int m = 0; m < 4; ++m) {
        const int row = wr * 64 + m * 16 + l15;
        afr[m] = *reinterpret_cast<const bf16x8*>(
            &Ab[row * 64 + (((kk * 4 + kq) ^ (row & 7)) * 8)]);
      }
      __builtin_amdgcn_s_setprio(1);
#pragma unroll
      for (int m = 0; m < 4; ++m)
#pragma unroll
        for (int g = 0; g < 4; ++g)
          acc[m][g] = __builtin_amdgcn_mfma_f32_16x16x32_bf16(
              afr[m], bfr[kk][g], acc[m][g], 0, 0, 0);
      __builtin_amdgcn_s_setprio(0);
    }

    if (s + 1 < NSTAGE) {
      if ((s & 1) == 0) stage_write((s + 1) & 1, avB);
      else              stage_write((s + 1) & 1, avA);
      BAR();
    }
  }

  // ---- epilogue: lane-local gate combine (D: col=lane&15, row=kq*4+e) ----
  float* obase  = out + (size_t)(mt * 128 + wr * 64 + kq * 4) * HDIM + ch;
  float* obase2 = obase + (size_t)NROWS * HDIM;
#pragma unroll
  for (int m = 0; m < 4; ++m) {
#pragma unroll
    for (int e = 0; e < 4; ++e) {
      const float pi = acc[m][0][e] + bias[0];
      const float pf = acc[m][1][e] + bias[1];
      const float pg = acc[m][2][e] + bias[2];
      const float po = acc[m][3][e] + bias[3];
      const float ig = sigm(pi), fg = sigm(pf);
      const float gg = tanh_fast(pg), og = sigm(po);
      const float co = fg * cvv[m * 4 + e] + ig * gg;
      const float ho = og * tanh_fast(co);
      obase [(size_t)(m * 16 + e) * HDIM] = co;
      obase2[(size_t)(m * 16 + e) * HDIM] = ho;
    }
  }
}

extern "C" void kernel_launch(void* const* d_in, const int* in_sizes, int n_in,
                              void* d_out, int out_size, void* d_ws, size_t ws_size,
                              hipStream_t stream) {
  const float* x  = (const float*)d_in[0];
  const float* C  = (const float*)d_in[1];
  const float* h  = (const float*)d_in[2];
  const float* Wx = (const float*)d_in[3];
  const float* Wh = (const float*)d_in[4];
  const float* bx = (const float*)d_in[5];
  const float* bh = (const float*)d_in[6];
  float* o = (float*)d_out;
  unsigned short* Bt = (unsigned short*)d_ws;   // 768*512*2 = 786 KiB

  prep_w<<<dim3(192), dim3(256), 0, stream>>>(Wx, Wh, Bt);
  lstm_main<<<dim3(8192), dim3(256), 0, stream>>>(x, C, h, Bt, bx, bh, o);
}